// Round 1
// baseline (290.920 us; speedup 1.0000x reference)
//
#include <hip/hip_runtime.h>
#include <stdint.h>

// mean(|x|) > 1.0 over D=128  <=>  sum(|x|) > 128.0
// Rows with bf16-estimated sum|x| > FLAG_THRESH go to the exact-fp32 fixup
// kernel (covers all branch-1 rows plus borderline rows; ~35 of 262144).
#define FLAG_THRESH 127.0f

typedef short bfrag __attribute__((ext_vector_type(8)));   // 8 bf16 (4 VGPRs)
typedef float floatx4 __attribute__((ext_vector_type(4))); // MFMA acc
typedef int intx4 __attribute__((ext_vector_type(4)));

__device__ __forceinline__ unsigned bf16pk(float a, float b) {  // RNE pack
    unsigned ua = __float_as_uint(a), ub = __float_as_uint(b);
    ua = (ua + 0x7fffu + ((ua >> 16) & 1u)) >> 16;
    ub = (ub + 0x7fffu + ((ub >> 16) & 1u)) & 0xffff0000u;
    return ua | ub;
}
__device__ __forceinline__ unsigned short bf16s(float a) {      // RNE scalar
    unsigned ua = __float_as_uint(a);
    return (unsigned short)((ua + 0x7fffu + ((ua >> 16) & 1u)) >> 16);
}
__device__ __forceinline__ bfrag mkfrag(unsigned a, unsigned b, unsigned c, unsigned d) {
    intx4 v = {(int)a, (int)b, (int)c, (int)d};
    return __builtin_bit_cast(bfrag, v);
}
// lgkmcnt(0)-only wait (vmcnt/expcnt bits all-ones), wave-local
__device__ __forceinline__ void lds_fence_wave() {
    __builtin_amdgcn_wave_barrier();
    __builtin_amdgcn_s_waitcnt(0xc07f);
    __builtin_amdgcn_wave_barrier();
}

// ---------------------------------------------------------------------------
// Main kernel: branch-2 path for ALL rows via bf16 MFMA; flags suspicious rows.
//   stage1: S(16x32) = x(16x128) @ W2^T  (+ ones-column for sum|x|)
//   H = relu(S + b2)  -> LDS (bf16)
//   stage2 (transposed): out^T(128x16) = Wf[:, :32](128x32) @ H^T(32x16)
// 1792 blocks x 256 thr = 7168 waves (7 blocks/CU, LDS-capped; 28 waves/CU).
// Occupancy was the bottleneck at 512 blocks (17% occ, 29% HBM, pipes idle).
// ---------------------------------------------------------------------------
__global__ __launch_bounds__(256, 7)
void dyn_main(const float* __restrict__ x, const float* __restrict__ W2,
              const float* __restrict__ b2, const float* __restrict__ Wf,
              const float* __restrict__ bf, float* __restrict__ out,
              int ntiles, int* __restrict__ ws, int cap)
{
    // weight fragments pre-gathered in lane order -> conflict-free b128 reads
    __shared__ __align__(16) short w2f[8][64][8];   // [ks*2+nb][lane][j]
    __shared__ __align__(16) short wff[8][64][8];   // [mb][lane][j]
    __shared__ __align__(16) float bfl[128];
    __shared__ __align__(16) short hbuf[4][16 * 40]; // per-wave H, stride 40

    const int tid  = threadIdx.x;
    const int wave = tid >> 6, lane = tid & 63;
    const int l15  = lane & 15, q = lane >> 4;

    // ---- stage weights into LDS (once per block) ----
    for (int idx = tid; idx < 4096; idx += 256) {
        const int j = idx & 7, ln = (idx >> 3) & 63, blk = idx >> 9;
        // W2 frag: blk = ks*2+nb ; element W2[nb*16 + (ln&15)][ks*32 + (ln>>4)*8 + j]
        const int ks = blk >> 1, nb = blk & 1;
        const int u = nb * 16 + (ln & 15);
        const int k = ks * 32 + ((ln >> 4) << 3) + j;
        ((short*)w2f)[idx] = (short)bf16s(W2[u * 128 + k]);
        // Wf frag: blk = mb ; element Wf[mb*16 + (ln&15)][(ln>>4)*8 + j], c < 32
        const int d = blk * 16 + (ln & 15);
        const int c = ((ln >> 4) << 3) + j;
        ((short*)wff)[idx] = (short)bf16s(Wf[d * 64 + c]);
    }
    for (int i = tid; i < 128; i += 256) bfl[i] = bf[i];
    const float b2r0 = b2[l15], b2r1 = b2[16 + l15];
    __syncthreads();

    // ones-column B fragment: B[k][n] = (n==0) ? 1.0bf16 : 0
    const unsigned ov = (l15 == 0) ? 0x3f803f80u : 0u;
    const bfrag onesf = mkfrag(ov, ov, ov, ov);

    const int wid = blockIdx.x * 4 + wave;
    const int wstride = gridDim.x * 4;

    long long cur = wid;
    bool more = cur < ntiles;
    floatx4 xl[8];
    if (more) {
        const float* base = x + cur * 2048 + l15 * 128 + q * 8;
        #pragma unroll
        for (int ks = 0; ks < 4; ++ks) {
            xl[2 * ks]     = *(const floatx4*)(base + ks * 32);
            xl[2 * ks + 1] = *(const floatx4*)(base + ks * 32 + 4);
        }
    }

    while (more) {
        const long long nxt = cur + wstride;
        const bool hasnxt = nxt < ntiles;
        floatx4 xc[8];
        #pragma unroll
        for (int i = 0; i < 8; ++i) xc[i] = xl[i];
        if (hasnxt) {   // register prefetch of next tile (kept in flight)
            const float* base = x + nxt * 2048 + l15 * 128 + q * 8;
            #pragma unroll
            for (int ks = 0; ks < 4; ++ks) {
                xl[2 * ks]     = *(const floatx4*)(base + ks * 32);
                xl[2 * ks + 1] = *(const floatx4*)(base + ks * 32 + 4);
            }
        }

        // ---- stage 1 ----
        floatx4 a0 = {0.f, 0.f, 0.f, 0.f}, a1 = a0, asum = a0;
        #pragma unroll
        for (int ks = 0; ks < 4; ++ks) {
            const floatx4 p = xc[2 * ks], r = xc[2 * ks + 1];
            const unsigned u0 = bf16pk(p[0], p[1]), u1 = bf16pk(p[2], p[3]);
            const unsigned u2 = bf16pk(r[0], r[1]), u3 = bf16pk(r[2], r[3]);
            const bfrag af = mkfrag(u0, u1, u2, u3);
            const bfrag aa = mkfrag(u0 & 0x7fff7fffu, u1 & 0x7fff7fffu,
                                    u2 & 0x7fff7fffu, u3 & 0x7fff7fffu);
            const bfrag w0 = *(const bfrag*)&w2f[ks * 2 + 0][lane][0];
            const bfrag w1 = *(const bfrag*)&w2f[ks * 2 + 1][lane][0];
            a0   = __builtin_amdgcn_mfma_f32_16x16x32_bf16(af, w0, a0, 0, 0, 0);
            a1   = __builtin_amdgcn_mfma_f32_16x16x32_bf16(af, w1, a1, 0, 0, 0);
            asum = __builtin_amdgcn_mfma_f32_16x16x32_bf16(aa, onesf, asum, 0, 0, 0);
        }

        // H = relu(S + b2) -> LDS bf16.  C-layout: row=q*4+reg, col=nb*16+l15
        short* hb = &hbuf[wave][0];
        #pragma unroll
        for (int reg = 0; reg < 4; ++reg) {
            const int row = q * 4 + reg;
            hb[row * 40 + l15]      = (short)bf16s(fmaxf(a0[reg] + b2r0, 0.f));
            hb[row * 40 + 16 + l15] = (short)bf16s(fmaxf(a1[reg] + b2r1, 0.f));
        }

        // flag branch-1 / borderline rows (abs-sums live in col 0 -> l15==0)
        if (l15 == 0) {
            #pragma unroll
            for (int reg = 0; reg < 4; ++reg) {
                if (asum[reg] > FLAG_THRESH) {
                    const int row = (int)(cur * 16) + q * 4 + reg;
                    const int slot = atomicAdd(ws, 1);
                    if (slot < cap) ws[4 + slot] = row;
                }
            }
        }

        lds_fence_wave();

        // ---- stage 2 (transposed): A = Wf slice, B = H^T ----
        const bfrag hfrag = *(const bfrag*)&hb[l15 * 40 + q * 8];
        floatx4 o[8];
        #pragma unroll
        for (int mb = 0; mb < 8; ++mb) o[mb] = (floatx4){0.f, 0.f, 0.f, 0.f};
        #pragma unroll
        for (int mb = 0; mb < 8; ++mb) {
            const bfrag wfr = *(const bfrag*)&wff[mb][lane][0];
            o[mb] = __builtin_amdgcn_mfma_f32_16x16x32_bf16(wfr, hfrag, o[mb], 0, 0, 0);
        }

        // C-layout: lane holds out[row = cur*16 + l15][d = mb*16 + q*4 + reg]
        float* obase = out + (cur * 16 + l15) * 128 + q * 4;
        #pragma unroll
        for (int mb = 0; mb < 8; ++mb) {
            const floatx4 bv = *(const floatx4*)&bfl[mb * 16 + q * 4];
            const floatx4 v = o[mb] + bv;
            *(floatx4*)(obase + mb * 16) = v;
        }

        lds_fence_wave();   // hfrag read drained before next iter's H writes
        cur = nxt; more = hasnxt;
    }
}

// ---------------------------------------------------------------------------
// Fixup: exact fp32 recompute (both branches) for flagged rows. One wave/row.
// ---------------------------------------------------------------------------
__global__ __launch_bounds__(256)
void dyn_fixup(const float* __restrict__ x, const float* __restrict__ W1,
               const float* __restrict__ b1, const float* __restrict__ W2,
               const float* __restrict__ b2, const float* __restrict__ Wf,
               const float* __restrict__ bf, float* __restrict__ out,
               const int* __restrict__ ws, int cap)
{
    __shared__ float xr[4][128];
    __shared__ float hh[4][64];
    const int wave = threadIdx.x >> 6, lane = threadIdx.x & 63;
    int n = ws[0]; if (n > cap) n = cap;
    for (int i = blockIdx.x * 4 + wave; i < n; i += gridDim.x * 4) {
        const int r = ws[4 + i];
        const float2 xv = *(const float2*)&x[(long long)r * 128 + lane * 2];
        float s = fabsf(xv.x) + fabsf(xv.y);
        #pragma unroll
        for (int d = 1; d < 64; d <<= 1) s += __shfl_xor(s, d);
        xr[wave][lane * 2] = xv.x; xr[wave][lane * 2 + 1] = xv.y;
        lds_fence_wave();
        float hv = 0.f;
        if (s > 128.0f) {                    // branch 1: 64 units of W1
            float a = 0.f;
            for (int k = 0; k < 128; k += 4) {
                const float4 qq = *(const float4*)&xr[wave][k];
                const float4 wv = *(const float4*)&W1[lane * 128 + k];
                a = fmaf(qq.x, wv.x, a); a = fmaf(qq.y, wv.y, a);
                a = fmaf(qq.z, wv.z, a); a = fmaf(qq.w, wv.w, a);
            }
            hv = fmaxf(a + b1[lane], 0.f);
        } else if (lane < 32) {              // branch 2: 32 units of W2
            float a = 0.f;
            for (int k = 0; k < 128; k += 4) {
                const float4 qq = *(const float4*)&xr[wave][k];
                const float4 wv = *(const float4*)&W2[lane * 128 + k];
                a = fmaf(qq.x, wv.x, a); a = fmaf(qq.y, wv.y, a);
                a = fmaf(qq.z, wv.z, a); a = fmaf(qq.w, wv.w, a);
            }
            hv = fmaxf(a + b2[lane], 0.f);
        }
        hh[wave][lane] = hv;                 // zero-padded for branch 2
        lds_fence_wave();
        #pragma unroll
        for (int jj = 0; jj < 2; ++jj) {
            const int d = lane + 64 * jj;
            float a = bf[d];
            for (int u = 0; u < 64; ++u) a = fmaf(hh[wave][u], Wf[d * 64 + u], a);
            out[(long long)r * 128 + d] = a;
        }
        lds_fence_wave();
    }
}

extern "C" void kernel_launch(void* const* d_in, const int* in_sizes, int n_in,
                              void* d_out, int out_size, void* d_ws, size_t ws_size,
                              hipStream_t stream) {
    const float* x  = (const float*)d_in[0];
    const float* W1 = (const float*)d_in[1];
    const float* b1 = (const float*)d_in[2];
    const float* W2 = (const float*)d_in[3];
    const float* b2 = (const float*)d_in[4];
    const float* Wf = (const float*)d_in[5];
    const float* bf = (const float*)d_in[6];
    float* out = (float*)d_out;

    const int B = in_sizes[0] / 128;   // D = 128
    const int ntiles = B / 16;         // 16384 for B=262144
    const int cap = (int)((ws_size > 16) ? ((ws_size - 16) / 4) : 0);

    hipMemsetAsync(d_ws, 0, 16, stream);   // zero the flagged-row counter
    // 1792 blocks = 7 blocks/CU (LDS-capped at 22 KiB/block) -> 28 waves/CU.
    // 512 (2/CU) left all pipes idle: occ 17%, HBM 29%, latency-bound.
    hipLaunchKernelGGL(dyn_main, dim3(1792), dim3(256), 0, stream,
                       x, W2, b2, Wf, bf, out, ntiles, (int*)d_ws, cap);
    hipLaunchKernelGGL(dyn_fixup, dim3(64), dim3(256), 0, stream,
                       x, W1, b1, W2, b2, Wf, bf, out, (int*)d_ws, cap);
}

// Round 2
// 264.058 us; speedup vs baseline: 1.1017x; 1.1017x over previous
//
#include <hip/hip_runtime.h>
#include <stdint.h>

// mean(|x|) > 1.0 over D=128  <=>  sum(|x|) > 128.0
// Rows with bf16-estimated sum|x| > FLAG_THRESH go to the exact-fp32 fixup
// kernel (covers all branch-1 rows plus borderline rows; ~35 of 262144).
#define FLAG_THRESH 127.0f

typedef short bfrag __attribute__((ext_vector_type(8)));   // 8 bf16 (4 VGPRs)
typedef float floatx4 __attribute__((ext_vector_type(4))); // MFMA acc
typedef int intx4 __attribute__((ext_vector_type(4)));

__device__ __forceinline__ unsigned bf16pk(float a, float b) {  // RNE pack
    unsigned ua = __float_as_uint(a), ub = __float_as_uint(b);
    ua = (ua + 0x7fffu + ((ua >> 16) & 1u)) >> 16;
    ub = (ub + 0x7fffu + ((ub >> 16) & 1u)) & 0xffff0000u;
    return ua | ub;
}
__device__ __forceinline__ unsigned short bf16s(float a) {      // RNE scalar
    unsigned ua = __float_as_uint(a);
    return (unsigned short)((ua + 0x7fffu + ((ua >> 16) & 1u)) >> 16);
}
__device__ __forceinline__ bfrag mkfrag(unsigned a, unsigned b, unsigned c, unsigned d) {
    intx4 v = {(int)a, (int)b, (int)c, (int)d};
    return __builtin_bit_cast(bfrag, v);
}
// lgkmcnt(0)-only wait (vmcnt/expcnt bits all-ones), wave-local
__device__ __forceinline__ void lds_fence_wave() {
    __builtin_amdgcn_wave_barrier();
    __builtin_amdgcn_s_waitcnt(0xc07f);
    __builtin_amdgcn_wave_barrier();
}

// ---------------------------------------------------------------------------
// Main kernel: branch-2 path for ALL rows via bf16 MFMA; flags suspicious rows.
//   stage1: S(16x32) = x(16x128) @ W2^T  (+ ones-column for sum|x|)
//   H = relu(S + b2)  -> LDS (bf16)
//   stage2 (transposed): out^T(128x16) = Wf[:, :32](128x32) @ H^T(32x16)
//
// Occupancy history:
//   2 blocks/CU (512):  occ 17%, clean traffic (204 MB), 2.34 TB/s, 87 us —
//                       latency-bound, pipes idle.
//   7 blocks/CU (1792): occ 54% BUT launch_bounds(256,7) cut VGPR to 36
//                       (killed the xl[] prefetch) and per-XCD in-flight
//                       write footprint (32CUx28wavesx8KB ~ 7MB) overflowed
//                       the 4MB XCD L2 -> partial-line evictions: WRITE
//                       133->227MB, FETCH 66->100MB, 111 us. WORSE.
//   4 blocks/CU (1024): this version. VGPR cap 128 (prefetch intact),
//                       write footprint ~4MB = L2 size, 4 tiles/wave exact.
// ---------------------------------------------------------------------------
__global__ __launch_bounds__(256, 4)
void dyn_main(const float* __restrict__ x, const float* __restrict__ W2,
              const float* __restrict__ b2, const float* __restrict__ Wf,
              const float* __restrict__ bf, float* __restrict__ out,
              int ntiles, int* __restrict__ ws, int cap)
{
    // weight fragments pre-gathered in lane order -> conflict-free b128 reads
    __shared__ __align__(16) short w2f[8][64][8];   // [ks*2+nb][lane][j]
    __shared__ __align__(16) short wff[8][64][8];   // [mb][lane][j]
    __shared__ __align__(16) float bfl[128];
    __shared__ __align__(16) short hbuf[4][16 * 40]; // per-wave H, stride 40

    const int tid  = threadIdx.x;
    const int wave = tid >> 6, lane = tid & 63;
    const int l15  = lane & 15, q = lane >> 4;

    // ---- stage weights into LDS (once per block) ----
    for (int idx = tid; idx < 4096; idx += 256) {
        const int j = idx & 7, ln = (idx >> 3) & 63, blk = idx >> 9;
        // W2 frag: blk = ks*2+nb ; element W2[nb*16 + (ln&15)][ks*32 + (ln>>4)*8 + j]
        const int ks = blk >> 1, nb = blk & 1;
        const int u = nb * 16 + (ln & 15);
        const int k = ks * 32 + ((ln >> 4) << 3) + j;
        ((short*)w2f)[idx] = (short)bf16s(W2[u * 128 + k]);
        // Wf frag: blk = mb ; element Wf[mb*16 + (ln&15)][(ln>>4)*8 + j], c < 32
        const int d = blk * 16 + (ln & 15);
        const int c = ((ln >> 4) << 3) + j;
        ((short*)wff)[idx] = (short)bf16s(Wf[d * 64 + c]);
    }
    for (int i = tid; i < 128; i += 256) bfl[i] = bf[i];
    const float b2r0 = b2[l15], b2r1 = b2[16 + l15];
    __syncthreads();

    // ones-column B fragment: B[k][n] = (n==0) ? 1.0bf16 : 0
    const unsigned ov = (l15 == 0) ? 0x3f803f80u : 0u;
    const bfrag onesf = mkfrag(ov, ov, ov, ov);

    const int wid = blockIdx.x * 4 + wave;
    const int wstride = gridDim.x * 4;

    long long cur = wid;
    bool more = cur < ntiles;
    floatx4 xl[8];
    if (more) {
        const float* base = x + cur * 2048 + l15 * 128 + q * 8;
        #pragma unroll
        for (int ks = 0; ks < 4; ++ks) {
            xl[2 * ks]     = *(const floatx4*)(base + ks * 32);
            xl[2 * ks + 1] = *(const floatx4*)(base + ks * 32 + 4);
        }
    }

    while (more) {
        const long long nxt = cur + wstride;
        const bool hasnxt = nxt < ntiles;
        floatx4 xc[8];
        #pragma unroll
        for (int i = 0; i < 8; ++i) xc[i] = xl[i];
        if (hasnxt) {   // register prefetch of next tile (kept in flight)
            const float* base = x + nxt * 2048 + l15 * 128 + q * 8;
            #pragma unroll
            for (int ks = 0; ks < 4; ++ks) {
                xl[2 * ks]     = *(const floatx4*)(base + ks * 32);
                xl[2 * ks + 1] = *(const floatx4*)(base + ks * 32 + 4);
            }
        }

        // ---- stage 1 ----
        floatx4 a0 = {0.f, 0.f, 0.f, 0.f}, a1 = a0, asum = a0;
        #pragma unroll
        for (int ks = 0; ks < 4; ++ks) {
            const floatx4 p = xc[2 * ks], r = xc[2 * ks + 1];
            const unsigned u0 = bf16pk(p[0], p[1]), u1 = bf16pk(p[2], p[3]);
            const unsigned u2 = bf16pk(r[0], r[1]), u3 = bf16pk(r[2], r[3]);
            const bfrag af = mkfrag(u0, u1, u2, u3);
            const bfrag aa = mkfrag(u0 & 0x7fff7fffu, u1 & 0x7fff7fffu,
                                    u2 & 0x7fff7fffu, u3 & 0x7fff7fffu);
            const bfrag w0 = *(const bfrag*)&w2f[ks * 2 + 0][lane][0];
            const bfrag w1 = *(const bfrag*)&w2f[ks * 2 + 1][lane][0];
            a0   = __builtin_amdgcn_mfma_f32_16x16x32_bf16(af, w0, a0, 0, 0, 0);
            a1   = __builtin_amdgcn_mfma_f32_16x16x32_bf16(af, w1, a1, 0, 0, 0);
            asum = __builtin_amdgcn_mfma_f32_16x16x32_bf16(aa, onesf, asum, 0, 0, 0);
        }

        // H = relu(S + b2) -> LDS bf16.  C-layout: row=q*4+reg, col=nb*16+l15
        short* hb = &hbuf[wave][0];
        #pragma unroll
        for (int reg = 0; reg < 4; ++reg) {
            const int row = q * 4 + reg;
            hb[row * 40 + l15]      = (short)bf16s(fmaxf(a0[reg] + b2r0, 0.f));
            hb[row * 40 + 16 + l15] = (short)bf16s(fmaxf(a1[reg] + b2r1, 0.f));
        }

        // flag branch-1 / borderline rows (abs-sums live in col 0 -> l15==0)
        if (l15 == 0) {
            #pragma unroll
            for (int reg = 0; reg < 4; ++reg) {
                if (asum[reg] > FLAG_THRESH) {
                    const int row = (int)(cur * 16) + q * 4 + reg;
                    const int slot = atomicAdd(ws, 1);
                    if (slot < cap) ws[4 + slot] = row;
                }
            }
        }

        lds_fence_wave();

        // ---- stage 2 (transposed): A = Wf slice, B = H^T ----
        const bfrag hfrag = *(const bfrag*)&hb[l15 * 40 + q * 8];
        floatx4 o[8];
        #pragma unroll
        for (int mb = 0; mb < 8; ++mb) o[mb] = (floatx4){0.f, 0.f, 0.f, 0.f};
        #pragma unroll
        for (int mb = 0; mb < 8; ++mb) {
            const bfrag wfr = *(const bfrag*)&wff[mb][lane][0];
            o[mb] = __builtin_amdgcn_mfma_f32_16x16x32_bf16(wfr, hfrag, o[mb], 0, 0, 0);
        }

        // C-layout: lane holds out[row = cur*16 + l15][d = mb*16 + q*4 + reg]
        float* obase = out + (cur * 16 + l15) * 128 + q * 4;
        #pragma unroll
        for (int mb = 0; mb < 8; ++mb) {
            const floatx4 bv = *(const floatx4*)&bfl[mb * 16 + q * 4];
            const floatx4 v = o[mb] + bv;
            *(floatx4*)(obase + mb * 16) = v;
        }

        lds_fence_wave();   // hfrag read drained before next iter's H writes
        cur = nxt; more = hasnxt;
    }
}

// ---------------------------------------------------------------------------
// Fixup: exact fp32 recompute (both branches) for flagged rows. One wave/row.
// ---------------------------------------------------------------------------
__global__ __launch_bounds__(256)
void dyn_fixup(const float* __restrict__ x, const float* __restrict__ W1,
               const float* __restrict__ b1, const float* __restrict__ W2,
               const float* __restrict__ b2, const float* __restrict__ Wf,
               const float* __restrict__ bf, float* __restrict__ out,
               const int* __restrict__ ws, int cap)
{
    __shared__ float xr[4][128];
    __shared__ float hh[4][64];
    const int wave = threadIdx.x >> 6, lane = threadIdx.x & 63;
    int n = ws[0]; if (n > cap) n = cap;
    for (int i = blockIdx.x * 4 + wave; i < n; i += gridDim.x * 4) {
        const int r = ws[4 + i];
        const float2 xv = *(const float2*)&x[(long long)r * 128 + lane * 2];
        float s = fabsf(xv.x) + fabsf(xv.y);
        #pragma unroll
        for (int d = 1; d < 64; d <<= 1) s += __shfl_xor(s, d);
        xr[wave][lane * 2] = xv.x; xr[wave][lane * 2 + 1] = xv.y;
        lds_fence_wave();
        float hv = 0.f;
        if (s > 128.0f) {                    // branch 1: 64 units of W1
            float a = 0.f;
            for (int k = 0; k < 128; k += 4) {
                const float4 qq = *(const float4*)&xr[wave][k];
                const float4 wv = *(const float4*)&W1[lane * 128 + k];
                a = fmaf(qq.x, wv.x, a); a = fmaf(qq.y, wv.y, a);
                a = fmaf(qq.z, wv.z, a); a = fmaf(qq.w, wv.w, a);
            }
            hv = fmaxf(a + b1[lane], 0.f);
        } else if (lane < 32) {              // branch 2: 32 units of W2
            float a = 0.f;
            for (int k = 0; k < 128; k += 4) {
                const float4 qq = *(const float4*)&xr[wave][k];
                const float4 wv = *(const float4*)&W2[lane * 128 + k];
                a = fmaf(qq.x, wv.x, a); a = fmaf(qq.y, wv.y, a);
                a = fmaf(qq.z, wv.z, a); a = fmaf(qq.w, wv.w, a);
            }
            hv = fmaxf(a + b2[lane], 0.f);
        }
        hh[wave][lane] = hv;                 // zero-padded for branch 2
        lds_fence_wave();
        #pragma unroll
        for (int jj = 0; jj < 2; ++jj) {
            const int d = lane + 64 * jj;
            float a = bf[d];
            for (int u = 0; u < 64; ++u) a = fmaf(hh[wave][u], Wf[d * 64 + u], a);
            out[(long long)r * 128 + d] = a;
        }
        lds_fence_wave();
    }
}

extern "C" void kernel_launch(void* const* d_in, const int* in_sizes, int n_in,
                              void* d_out, int out_size, void* d_ws, size_t ws_size,
                              hipStream_t stream) {
    const float* x  = (const float*)d_in[0];
    const float* W1 = (const float*)d_in[1];
    const float* b1 = (const float*)d_in[2];
    const float* W2 = (const float*)d_in[3];
    const float* b2 = (const float*)d_in[4];
    const float* Wf = (const float*)d_in[5];
    const float* bf = (const float*)d_in[6];
    float* out = (float*)d_out;

    const int B = in_sizes[0] / 128;   // D = 128
    const int ntiles = B / 16;         // 16384 for B=262144
    const int cap = (int)((ws_size > 16) ? ((ws_size - 16) / 4) : 0);

    hipMemsetAsync(d_ws, 0, 16, stream);   // zero the flagged-row counter
    // 1024 blocks = 4 blocks/CU (16 waves/CU). 2/CU was latency-bound (17%
    // occ, 2.3 TB/s); 7/CU thrashed L2 write-combining (WRITE 133->227 MB)
    // and squeezed VGPR to 36 (prefetch killed). 4/CU: VGPR cap 128, write
    // footprint ~4 MB/XCD = L2 size, 16384/4096 = 4 tiles/wave exact.
    hipLaunchKernelGGL(dyn_main, dim3(1024), dim3(256), 0, stream,
                       x, W2, b2, Wf, bf, out, ntiles, (int*)d_ws, cap);
    hipLaunchKernelGGL(dyn_fixup, dim3(64), dim3(256), 0, stream,
                       x, W1, b1, W2, b2, Wf, bf, out, (int*)d_ws, cap);
}

// Round 3
// 262.184 us; speedup vs baseline: 1.1096x; 1.0071x over previous
//
#include <hip/hip_runtime.h>
#include <stdint.h>

// mean(|x|) > 1.0 over D=128  <=>  sum(|x|) > 128.0
// Rows with bf16-estimated sum|x| > FLAG_THRESH get an exact-fp32 in-wave
// recompute (covers all branch-1 rows plus borderline rows; ~35 of 262144).
#define FLAG_THRESH 127.0f

typedef short bfrag __attribute__((ext_vector_type(8)));   // 8 bf16 (4 VGPRs)
typedef float floatx4 __attribute__((ext_vector_type(4))); // MFMA acc
typedef int intx4 __attribute__((ext_vector_type(4)));

__device__ __forceinline__ unsigned bf16pk(float a, float b) {  // RNE pack
    unsigned ua = __float_as_uint(a), ub = __float_as_uint(b);
    ua = (ua + 0x7fffu + ((ua >> 16) & 1u)) >> 16;
    ub = (ub + 0x7fffu + ((ub >> 16) & 1u)) & 0xffff0000u;
    return ua | ub;
}
__device__ __forceinline__ unsigned short bf16s(float a) {      // RNE scalar
    unsigned ua = __float_as_uint(a);
    return (unsigned short)((ua + 0x7fffu + ((ua >> 16) & 1u)) >> 16);
}
__device__ __forceinline__ bfrag mkfrag(unsigned a, unsigned b, unsigned c, unsigned d) {
    intx4 v = {(int)a, (int)b, (int)c, (int)d};
    return __builtin_bit_cast(bfrag, v);
}
// lgkmcnt(0)-only wait (vmcnt/expcnt bits all-ones), wave-local
__device__ __forceinline__ void lds_fence_wave() {
    __builtin_amdgcn_wave_barrier();
    __builtin_amdgcn_s_waitcnt(0xc07f);
    __builtin_amdgcn_wave_barrier();
}

// ---------------------------------------------------------------------------
// SINGLE-DISPATCH kernel. Branch-2 path for ALL rows via bf16 MFMA; rows whose
// bf16 sum|x| is suspicious (> FLAG_THRESH) are recomputed exactly IN-WAVE
// (the wave still holds the row's fp32 data in registers), replacing the old
// {memset, main, fixup} 3-dispatch pipeline.
//
// History:
//   2 blk/CU: occ 17%, 204 MB clean, 2.34 TB/s, main 87 us.
//   7 blk/CU: launch_bounds VGPR squeeze (36) + L2 write thrash (WRITE
//             133->227 MB): 111 us. WORSE.
//   4 blk/CU: VGPR 52, clean 204 MB, 2.34 TB/s, 87 us — identical to 2/CU.
//   => main loop pinned at ~87 us independent of launch geometry; but
//      dur_us = main + ~178 us constant across all rounds (3 dispatches).
//      This version attacks the constant: 1 dispatch, no workspace.
// ---------------------------------------------------------------------------
__global__ __launch_bounds__(256, 4)
void dyn_main(const float* __restrict__ x, const float* __restrict__ W1,
              const float* __restrict__ b1, const float* __restrict__ W2,
              const float* __restrict__ b2, const float* __restrict__ Wf,
              const float* __restrict__ bf, float* __restrict__ out,
              int ntiles)
{
    // weight fragments pre-gathered in lane order -> conflict-free b128 reads
    __shared__ __align__(16) short w2f[8][64][8];   // [ks*2+nb][lane][j]
    __shared__ __align__(16) short wff[8][64][8];   // [mb][lane][j]
    __shared__ __align__(16) float bfl[128];
    __shared__ __align__(16) short hbuf[4][16 * 40]; // per-wave H, stride 40
    __shared__ __align__(16) float xr[4][128];       // rare path: one fp32 row
    __shared__ __align__(16) float hh[4][64];        // rare path: exact hidden

    const int tid  = threadIdx.x;
    const int wave = tid >> 6, lane = tid & 63;
    const int l15  = lane & 15, q = lane >> 4;

    // ---- stage weights into LDS (once per block) ----
    for (int idx = tid; idx < 4096; idx += 256) {
        const int j = idx & 7, ln = (idx >> 3) & 63, blk = idx >> 9;
        // W2 frag: blk = ks*2+nb ; element W2[nb*16 + (ln&15)][ks*32 + (ln>>4)*8 + j]
        const int ks = blk >> 1, nb = blk & 1;
        const int u = nb * 16 + (ln & 15);
        const int k = ks * 32 + ((ln >> 4) << 3) + j;
        ((short*)w2f)[idx] = (short)bf16s(W2[u * 128 + k]);
        // Wf frag: blk = mb ; element Wf[mb*16 + (ln&15)][(ln>>4)*8 + j], c < 32
        const int d = blk * 16 + (ln & 15);
        const int c = ((ln >> 4) << 3) + j;
        ((short*)wff)[idx] = (short)bf16s(Wf[d * 64 + c]);
    }
    for (int i = tid; i < 128; i += 256) bfl[i] = bf[i];
    const float b2r0 = b2[l15], b2r1 = b2[16 + l15];
    __syncthreads();

    // ones-column B fragment: B[k][n] = (n==0) ? 1.0bf16 : 0
    const unsigned ov = (l15 == 0) ? 0x3f803f80u : 0u;
    const bfrag onesf = mkfrag(ov, ov, ov, ov);

    const int wid = blockIdx.x * 4 + wave;
    const int wstride = gridDim.x * 4;

    long long cur = wid;
    bool more = cur < ntiles;
    floatx4 xl[8];
    if (more) {
        const float* base = x + cur * 2048 + l15 * 128 + q * 8;
        #pragma unroll
        for (int ks = 0; ks < 4; ++ks) {
            xl[2 * ks]     = *(const floatx4*)(base + ks * 32);
            xl[2 * ks + 1] = *(const floatx4*)(base + ks * 32 + 4);
        }
    }

    while (more) {
        const long long nxt = cur + wstride;
        const bool hasnxt = nxt < ntiles;
        floatx4 xc[8];
        #pragma unroll
        for (int i = 0; i < 8; ++i) xc[i] = xl[i];
        if (hasnxt) {   // register prefetch of next tile (kept in flight)
            const float* base = x + nxt * 2048 + l15 * 128 + q * 8;
            #pragma unroll
            for (int ks = 0; ks < 4; ++ks) {
                xl[2 * ks]     = *(const floatx4*)(base + ks * 32);
                xl[2 * ks + 1] = *(const floatx4*)(base + ks * 32 + 4);
            }
        }

        // ---- stage 1 ----
        floatx4 a0 = {0.f, 0.f, 0.f, 0.f}, a1 = a0, asum = a0;
        #pragma unroll
        for (int ks = 0; ks < 4; ++ks) {
            const floatx4 p = xc[2 * ks], r = xc[2 * ks + 1];
            const unsigned u0 = bf16pk(p[0], p[1]), u1 = bf16pk(p[2], p[3]);
            const unsigned u2 = bf16pk(r[0], r[1]), u3 = bf16pk(r[2], r[3]);
            const bfrag af = mkfrag(u0, u1, u2, u3);
            const bfrag aa = mkfrag(u0 & 0x7fff7fffu, u1 & 0x7fff7fffu,
                                    u2 & 0x7fff7fffu, u3 & 0x7fff7fffu);
            const bfrag w0 = *(const bfrag*)&w2f[ks * 2 + 0][lane][0];
            const bfrag w1 = *(const bfrag*)&w2f[ks * 2 + 1][lane][0];
            a0   = __builtin_amdgcn_mfma_f32_16x16x32_bf16(af, w0, a0, 0, 0, 0);
            a1   = __builtin_amdgcn_mfma_f32_16x16x32_bf16(af, w1, a1, 0, 0, 0);
            asum = __builtin_amdgcn_mfma_f32_16x16x32_bf16(aa, onesf, asum, 0, 0, 0);
        }

        // ---- flag suspicious rows: wave-uniform 16-bit row mask ----
        // abs-sums live in col 0 of asum -> lanes with l15==0, row = q*4+reg
        unsigned rowmask = 0;
        #pragma unroll
        for (int reg = 0; reg < 4; ++reg) {
            const unsigned long long bm =
                __ballot(l15 == 0 && asum[reg] > FLAG_THRESH);
            rowmask |= (unsigned)( bm        & 1ull) << (0 + reg);
            rowmask |= (unsigned)((bm >> 16) & 1ull) << (4 + reg);
            rowmask |= (unsigned)((bm >> 32) & 1ull) << (8 + reg);
            rowmask |= (unsigned)((bm >> 48) & 1ull) << (12 + reg);
        }

        // ---- rare path (~35/16384 tiles): exact fp32 recompute in-wave ----
        // Numerics identical to the old dyn_fixup kernel (same op order).
        if (__builtin_expect(rowmask != 0, 0)) {
            unsigned m = rowmask;
            while (m) {
                const int r = (int)__builtin_ctz(m); m &= m - 1;
                // lanes with l15==r hold row r's fp32 values in xc
                if (l15 == r) {
                    #pragma unroll
                    for (int ks = 0; ks < 4; ++ks) {
                        *(floatx4*)&xr[wave][ks * 32 + q * 8]     = xc[2 * ks];
                        *(floatx4*)&xr[wave][ks * 32 + q * 8 + 4] = xc[2 * ks + 1];
                    }
                }
                lds_fence_wave();
                // exact sum|x| (same order as old fixup: pairwise + xor-tree)
                const float e0 = xr[wave][lane * 2], e1 = xr[wave][lane * 2 + 1];
                float s = fabsf(e0) + fabsf(e1);
                #pragma unroll
                for (int d = 1; d < 64; d <<= 1) s += __shfl_xor(s, d);
                float hv = 0.f;
                if (s > 128.0f) {                    // branch 1: 64 units of W1
                    float a = 0.f;
                    for (int k = 0; k < 128; k += 4) {
                        const float4 qq = *(const float4*)&xr[wave][k];
                        const float4 wv = *(const float4*)&W1[lane * 128 + k];
                        a = fmaf(qq.x, wv.x, a); a = fmaf(qq.y, wv.y, a);
                        a = fmaf(qq.z, wv.z, a); a = fmaf(qq.w, wv.w, a);
                    }
                    hv = fmaxf(a + b1[lane], 0.f);
                } else if (lane < 32) {              // branch 2: 32 units of W2
                    float a = 0.f;
                    for (int k = 0; k < 128; k += 4) {
                        const float4 qq = *(const float4*)&xr[wave][k];
                        const float4 wv = *(const float4*)&W2[lane * 128 + k];
                        a = fmaf(qq.x, wv.x, a); a = fmaf(qq.y, wv.y, a);
                        a = fmaf(qq.z, wv.z, a); a = fmaf(qq.w, wv.w, a);
                    }
                    hv = fmaxf(a + b2[lane], 0.f);
                }
                hh[wave][lane] = hv;                 // zero-padded for branch 2
                lds_fence_wave();
                #pragma unroll
                for (int jj = 0; jj < 2; ++jj) {
                    const int d = lane + 64 * jj;
                    float a = bf[d];
                    for (int u = 0; u < 64; ++u)
                        a = fmaf(hh[wave][u], Wf[d * 64 + u], a);
                    out[(cur * 16 + r) * 128 + d] = a;
                }
                lds_fence_wave();   // hh reads drained before next row reuse
            }
        }

        // H = relu(S + b2) -> LDS bf16.  C-layout: row=q*4+reg, col=nb*16+l15
        short* hb = &hbuf[wave][0];
        #pragma unroll
        for (int reg = 0; reg < 4; ++reg) {
            const int row = q * 4 + reg;
            hb[row * 40 + l15]      = (short)bf16s(fmaxf(a0[reg] + b2r0, 0.f));
            hb[row * 40 + 16 + l15] = (short)bf16s(fmaxf(a1[reg] + b2r1, 0.f));
        }

        lds_fence_wave();

        // ---- stage 2 (transposed): A = Wf slice, B = H^T ----
        const bfrag hfrag = *(const bfrag*)&hb[l15 * 40 + q * 8];
        floatx4 o[8];
        #pragma unroll
        for (int mb = 0; mb < 8; ++mb) o[mb] = (floatx4){0.f, 0.f, 0.f, 0.f};
        #pragma unroll
        for (int mb = 0; mb < 8; ++mb) {
            const bfrag wfr = *(const bfrag*)&wff[mb][lane][0];
            o[mb] = __builtin_amdgcn_mfma_f32_16x16x32_bf16(wfr, hfrag, o[mb], 0, 0, 0);
        }

        // C-layout: lane holds out[row = cur*16 + l15][d = mb*16 + q*4 + reg]
        float* obase = out + (cur * 16 + l15) * 128 + q * 4;
        if (__builtin_expect(rowmask == 0, 1)) {     // fast path: plain stores
            #pragma unroll
            for (int mb = 0; mb < 8; ++mb) {
                const floatx4 bv = *(const floatx4*)&bfl[mb * 16 + q * 4];
                const floatx4 v = o[mb] + bv;
                *(floatx4*)(obase + mb * 16) = v;
            }
        } else {                                     // skip exactly-fixed rows
            if (((rowmask >> l15) & 1u) == 0u) {
                #pragma unroll
                for (int mb = 0; mb < 8; ++mb) {
                    const floatx4 bv = *(const floatx4*)&bfl[mb * 16 + q * 4];
                    const floatx4 v = o[mb] + bv;
                    *(floatx4*)(obase + mb * 16) = v;
                }
            }
        }

        lds_fence_wave();   // hfrag read drained before next iter's H writes
        cur = nxt; more = hasnxt;
    }
}

extern "C" void kernel_launch(void* const* d_in, const int* in_sizes, int n_in,
                              void* d_out, int out_size, void* d_ws, size_t ws_size,
                              hipStream_t stream) {
    const float* x  = (const float*)d_in[0];
    const float* W1 = (const float*)d_in[1];
    const float* b1 = (const float*)d_in[2];
    const float* W2 = (const float*)d_in[3];
    const float* b2 = (const float*)d_in[4];
    const float* Wf = (const float*)d_in[5];
    const float* bf = (const float*)d_in[6];
    float* out = (float*)d_out;
    (void)d_ws; (void)ws_size;

    const int B = in_sizes[0] / 128;   // D = 128
    const int ntiles = B / 16;         // 16384 for B=262144

    // ONE dispatch (was memset + main + fixup). 1024 blocks = 4 blocks/CU.
    hipLaunchKernelGGL(dyn_main, dim3(1024), dim3(256), 0, stream,
                       x, W1, b1, W2, b2, Wf, bf, out, ntiles);
}

// Round 4
// 253.262 us; speedup vs baseline: 1.1487x; 1.0352x over previous
//
#include <hip/hip_runtime.h>
#include <stdint.h>

// mean(|x|) > 1.0 over D=128  <=>  sum(|x|) > 128.0
// Rows with bf16-estimated sum|x| > FLAG_THRESH get an exact-fp32 in-wave
// recompute (covers all branch-1 rows plus borderline rows; ~35 of 262144).
#define FLAG_THRESH 127.0f

typedef short bfrag __attribute__((ext_vector_type(8)));   // 8 bf16 (4 VGPRs)
typedef float floatx4 __attribute__((ext_vector_type(4))); // MFMA acc
typedef int intx4 __attribute__((ext_vector_type(4)));

__device__ __forceinline__ unsigned bf16pk(float a, float b) {  // RNE pack
    unsigned ua = __float_as_uint(a), ub = __float_as_uint(b);
    ua = (ua + 0x7fffu + ((ua >> 16) & 1u)) >> 16;
    ub = (ub + 0x7fffu + ((ub >> 16) & 1u)) & 0xffff0000u;
    return ua | ub;
}
__device__ __forceinline__ unsigned short bf16s(float a) {      // RNE scalar
    unsigned ua = __float_as_uint(a);
    return (unsigned short)((ua + 0x7fffu + ((ua >> 16) & 1u)) >> 16);
}
__device__ __forceinline__ bfrag mkfrag(unsigned a, unsigned b, unsigned c, unsigned d) {
    intx4 v = {(int)a, (int)b, (int)c, (int)d};
    return __builtin_bit_cast(bfrag, v);
}
// lgkmcnt(0)-only wait (vmcnt/expcnt bits all-ones), wave-local
__device__ __forceinline__ void lds_fence_wave() {
    __builtin_amdgcn_wave_barrier();
    __builtin_amdgcn_s_waitcnt(0xc07f);
    __builtin_amdgcn_wave_barrier();
}

// ---------------------------------------------------------------------------
// SINGLE-DISPATCH kernel with COALESCED STORES.
//
// Evidence so far: delivered BW pinned at 2.34 TB/s whether 8 or 16 waves/CU,
// all pipes <10% busy -> per-CU memory-path throughput cap, not latency, not
// occupancy. Through-CU traffic 268 MB / 87 us = 12 B/cyc/CU vs ~24.6 of a
// coalesced copy (m13). Fragment-layout stores write each 128-B line as TWO
// 64-B L2 transactions (stores bypass L1); this version transposes the output
// tile through LDS ([16][132] fp32, padded) so each global_store_dwordx4
// covers a contiguous 1 KB (8 full lines) per wave instruction.
//
// History: r0 2blk/CU 87us | r1 7blk/CU VGPR-spill 111us | r2 4blk/CU 87us |
// r3 fused 1-dispatch but store-block duplication inflated WRITE +20MB, 97us.
// ---------------------------------------------------------------------------
__global__ __launch_bounds__(256, 2)
void dyn_main(const float* __restrict__ x, const float* __restrict__ W1,
              const float* __restrict__ b1, const float* __restrict__ W2,
              const float* __restrict__ b2, const float* __restrict__ Wf,
              const float* __restrict__ bf, float* __restrict__ out,
              int ntiles)
{
    // weight fragments pre-gathered in lane order -> conflict-free b128 reads
    __shared__ __align__(16) short w2f[8][64][8];   // [ks*2+nb][lane][j]
    __shared__ __align__(16) short wff[8][64][8];   // [mb][lane][j]
    __shared__ __align__(16) float bfl[128];
    __shared__ __align__(16) short hbuf[4][16 * 40]; // per-wave H, stride 40
    __shared__ __align__(16) float ost[4][16][132];  // per-wave out-transpose
    __shared__ __align__(16) float xr[4][128];       // rare path: one fp32 row
    __shared__ __align__(16) float hh[4][64];        // rare path: exact hidden

    const int tid  = threadIdx.x;
    const int wave = tid >> 6, lane = tid & 63;
    const int l15  = lane & 15, q = lane >> 4;

    // ---- stage weights into LDS (once per block) ----
    for (int idx = tid; idx < 4096; idx += 256) {
        const int j = idx & 7, ln = (idx >> 3) & 63, blk = idx >> 9;
        // W2 frag: blk = ks*2+nb ; element W2[nb*16 + (ln&15)][ks*32 + (ln>>4)*8 + j]
        const int ks = blk >> 1, nb = blk & 1;
        const int u = nb * 16 + (ln & 15);
        const int k = ks * 32 + ((ln >> 4) << 3) + j;
        ((short*)w2f)[idx] = (short)bf16s(W2[u * 128 + k]);
        // Wf frag: blk = mb ; element Wf[mb*16 + (ln&15)][(ln>>4)*8 + j], c < 32
        const int d = blk * 16 + (ln & 15);
        const int c = ((ln >> 4) << 3) + j;
        ((short*)wff)[idx] = (short)bf16s(Wf[d * 64 + c]);
    }
    for (int i = tid; i < 128; i += 256) bfl[i] = bf[i];
    const float b2r0 = b2[l15], b2r1 = b2[16 + l15];
    __syncthreads();

    // ones-column B fragment: B[k][n] = (n==0) ? 1.0bf16 : 0
    const unsigned ov = (l15 == 0) ? 0x3f803f80u : 0u;
    const bfrag onesf = mkfrag(ov, ov, ov, ov);

    const int wid = blockIdx.x * 4 + wave;
    const int wstride = gridDim.x * 4;

    long long cur = wid;
    bool more = cur < ntiles;
    floatx4 xl[8];
    if (more) {
        const float* base = x + cur * 2048 + l15 * 128 + q * 8;
        #pragma unroll
        for (int ks = 0; ks < 4; ++ks) {
            xl[2 * ks]     = *(const floatx4*)(base + ks * 32);
            xl[2 * ks + 1] = *(const floatx4*)(base + ks * 32 + 4);
        }
    }

    while (more) {
        const long long nxt = cur + wstride;
        const bool hasnxt = nxt < ntiles;
        floatx4 xc[8];
        #pragma unroll
        for (int i = 0; i < 8; ++i) xc[i] = xl[i];
        if (hasnxt) {   // register prefetch of next tile (kept in flight)
            const float* base = x + nxt * 2048 + l15 * 128 + q * 8;
            #pragma unroll
            for (int ks = 0; ks < 4; ++ks) {
                xl[2 * ks]     = *(const floatx4*)(base + ks * 32);
                xl[2 * ks + 1] = *(const floatx4*)(base + ks * 32 + 4);
            }
        }

        // ---- stage 1 ----
        floatx4 a0 = {0.f, 0.f, 0.f, 0.f}, a1 = a0, asum = a0;
        #pragma unroll
        for (int ks = 0; ks < 4; ++ks) {
            const floatx4 p = xc[2 * ks], r = xc[2 * ks + 1];
            const unsigned u0 = bf16pk(p[0], p[1]), u1 = bf16pk(p[2], p[3]);
            const unsigned u2 = bf16pk(r[0], r[1]), u3 = bf16pk(r[2], r[3]);
            const bfrag af = mkfrag(u0, u1, u2, u3);
            const bfrag aa = mkfrag(u0 & 0x7fff7fffu, u1 & 0x7fff7fffu,
                                    u2 & 0x7fff7fffu, u3 & 0x7fff7fffu);
            const bfrag w0 = *(const bfrag*)&w2f[ks * 2 + 0][lane][0];
            const bfrag w1 = *(const bfrag*)&w2f[ks * 2 + 1][lane][0];
            a0   = __builtin_amdgcn_mfma_f32_16x16x32_bf16(af, w0, a0, 0, 0, 0);
            a1   = __builtin_amdgcn_mfma_f32_16x16x32_bf16(af, w1, a1, 0, 0, 0);
            asum = __builtin_amdgcn_mfma_f32_16x16x32_bf16(aa, onesf, asum, 0, 0, 0);
        }

        // ---- flag suspicious rows: wave-uniform 16-bit row mask ----
        // abs-sums live in col 0 of asum -> lanes with l15==0, row = q*4+reg
        unsigned rowmask = 0;
        #pragma unroll
        for (int reg = 0; reg < 4; ++reg) {
            const unsigned long long bm =
                __ballot(l15 == 0 && asum[reg] > FLAG_THRESH);
            rowmask |= (unsigned)( bm        & 1ull) << (0 + reg);
            rowmask |= (unsigned)((bm >> 16) & 1ull) << (4 + reg);
            rowmask |= (unsigned)((bm >> 32) & 1ull) << (8 + reg);
            rowmask |= (unsigned)((bm >> 48) & 1ull) << (12 + reg);
        }

        // ---- rare path (~35/16384 tiles): exact fp32 recompute in-wave ----
        // Numerics identical to the original fixup kernel (same op order).
        if (__builtin_expect(rowmask != 0, 0)) {
            unsigned m = rowmask;
            while (m) {
                const int r = (int)__builtin_ctz(m); m &= m - 1;
                // lanes with l15==r hold row r's fp32 values in xc
                if (l15 == r) {
                    #pragma unroll
                    for (int ks = 0; ks < 4; ++ks) {
                        *(floatx4*)&xr[wave][ks * 32 + q * 8]     = xc[2 * ks];
                        *(floatx4*)&xr[wave][ks * 32 + q * 8 + 4] = xc[2 * ks + 1];
                    }
                }
                lds_fence_wave();
                // exact sum|x| (same order as old fixup: pairwise + xor-tree)
                const float e0 = xr[wave][lane * 2], e1 = xr[wave][lane * 2 + 1];
                float s = fabsf(e0) + fabsf(e1);
                #pragma unroll
                for (int d = 1; d < 64; d <<= 1) s += __shfl_xor(s, d);
                float hv = 0.f;
                if (s > 128.0f) {                    // branch 1: 64 units of W1
                    float a = 0.f;
                    for (int k = 0; k < 128; k += 4) {
                        const float4 qq = *(const float4*)&xr[wave][k];
                        const float4 wv = *(const float4*)&W1[lane * 128 + k];
                        a = fmaf(qq.x, wv.x, a); a = fmaf(qq.y, wv.y, a);
                        a = fmaf(qq.z, wv.z, a); a = fmaf(qq.w, wv.w, a);
                    }
                    hv = fmaxf(a + b1[lane], 0.f);
                } else if (lane < 32) {              // branch 2: 32 units of W2
                    float a = 0.f;
                    for (int k = 0; k < 128; k += 4) {
                        const float4 qq = *(const float4*)&xr[wave][k];
                        const float4 wv = *(const float4*)&W2[lane * 128 + k];
                        a = fmaf(qq.x, wv.x, a); a = fmaf(qq.y, wv.y, a);
                        a = fmaf(qq.z, wv.z, a); a = fmaf(qq.w, wv.w, a);
                    }
                    hv = fmaxf(a + b2[lane], 0.f);
                }
                hh[wave][lane] = hv;                 // zero-padded for branch 2
                lds_fence_wave();
                #pragma unroll
                for (int jj = 0; jj < 2; ++jj) {
                    const int d = lane + 64 * jj;
                    float a = bf[d];
                    for (int u = 0; u < 64; ++u)
                        a = fmaf(hh[wave][u], Wf[d * 64 + u], a);
                    out[(cur * 16 + r) * 128 + d] = a;
                }
                lds_fence_wave();   // hh reads drained before next row reuse
            }
        }

        // H = relu(S + b2) -> LDS bf16.  C-layout: row=q*4+reg, col=nb*16+l15
        short* hb = &hbuf[wave][0];
        #pragma unroll
        for (int reg = 0; reg < 4; ++reg) {
            const int row = q * 4 + reg;
            hb[row * 40 + l15]      = (short)bf16s(fmaxf(a0[reg] + b2r0, 0.f));
            hb[row * 40 + 16 + l15] = (short)bf16s(fmaxf(a1[reg] + b2r1, 0.f));
        }

        lds_fence_wave();

        // ---- stage 2 (transposed): A = Wf slice, B = H^T ----
        const bfrag hfrag = *(const bfrag*)&hb[l15 * 40 + q * 8];
        floatx4 o[8];
        #pragma unroll
        for (int mb = 0; mb < 8; ++mb) o[mb] = (floatx4){0.f, 0.f, 0.f, 0.f};
        #pragma unroll
        for (int mb = 0; mb < 8; ++mb) {
            const bfrag wfr = *(const bfrag*)&wff[mb][lane][0];
            o[mb] = __builtin_amdgcn_mfma_f32_16x16x32_bf16(wfr, hfrag, o[mb], 0, 0, 0);
        }

        // ---- bias add + transpose through LDS ([16][132] pad -> ~2-way) ----
        // MFMA C-layout: lane holds out[row=l15][d = mb*16 + q*4 + reg]
        #pragma unroll
        for (int mb = 0; mb < 8; ++mb) {
            const floatx4 bv = *(const floatx4*)&bfl[mb * 16 + q * 4];
            const floatx4 v = o[mb] + bv;
            *(floatx4*)&ost[wave][l15][mb * 16 + q * 4] = v;
        }

        lds_fence_wave();

        // ---- coalesced store: 8 instr, each = 64 lanes x 16 B = 1 KB
        //      contiguous (8 full 128-B lines), vs old 64-B/line granule ----
        float* gbase = out + cur * 2048;
        #pragma unroll
        for (int c = 0; c < 8; ++c) {
            const int row = 2 * c + (lane >> 5);
            const int col = (lane & 31) * 4;
            const floatx4 v = *(const floatx4*)&ost[wave][row][col];
            if (((rowmask >> row) & 1u) == 0u)     // skip exactly-fixed rows
                *(floatx4*)(gbase + row * 128 + col) = v;
        }

        lds_fence_wave();   // ost/hbuf reads drained before next iter writes
        cur = nxt; more = hasnxt;
    }
}

extern "C" void kernel_launch(void* const* d_in, const int* in_sizes, int n_in,
                              void* d_out, int out_size, void* d_ws, size_t ws_size,
                              hipStream_t stream) {
    const float* x  = (const float*)d_in[0];
    const float* W1 = (const float*)d_in[1];
    const float* b1 = (const float*)d_in[2];
    const float* W2 = (const float*)d_in[3];
    const float* b2 = (const float*)d_in[4];
    const float* Wf = (const float*)d_in[5];
    const float* bf = (const float*)d_in[6];
    float* out = (float*)d_out;
    (void)d_ws; (void)ws_size;

    const int B = in_sizes[0] / 128;   // D = 128
    const int ntiles = B / 16;         // 16384 for B=262144

    // ONE dispatch. 512 blocks = 2 blocks/CU (LDS ~59 KB/block), 8 waves/CU —
    // proven equivalent to 16 waves/CU (r0 == r2: both 87 us); 16384/2048 =
    // 8 tiles/wave exact.
    hipLaunchKernelGGL(dyn_main, dim3(512), dim3(256), 0, stream,
                       x, W1, b1, W2, b2, Wf, bf, out, ntiles);
}